// Round 1
// baseline (6554.876 us; speedup 1.0000x reference)
//
#include <hip/hip_runtime.h>
#include <math.h>

#define V_SZ   32000
#define D_SZ   768
#define H_N    12
#define KVH_N  4
#define L_N    6
#define T_SEQ  1024
#define HD_SZ  64
#define KVD_SZ 256
#define B_SZ   2
#define M_TOK  (B_SZ * T_SEQ)   // 2048 token rows

// ---------------- block-wide sum over 256 threads (4 waves) ----------------
__device__ __forceinline__ float block_reduce_sum_256(float v, float* ws4) {
#pragma unroll
  for (int o = 32; o; o >>= 1) v += __shfl_xor(v, o, 64);
  int wid = threadIdx.x >> 6;
  if ((threadIdx.x & 63) == 0) ws4[wid] = v;
  __syncthreads();
  return ws4[0] + ws4[1] + ws4[2] + ws4[3];
}

// ---------------- embedding + RMSNorm; writes x and x0 ----------------
__global__ __launch_bounds__(256) void embed_norm_k(
    const int* __restrict__ idx, const float* __restrict__ wte,
    float* __restrict__ x, float* __restrict__ x0) {
  __shared__ float ws4[4];
  int bt = blockIdx.x;
  int tok = idx[bt];
  const float* row = wte + (size_t)tok * D_SZ;
  float v[3]; float ss = 0.f;
#pragma unroll
  for (int i = 0; i < 3; i++) { v[i] = row[threadIdx.x + i * 256]; ss += v[i] * v[i]; }
  ss = block_reduce_sum_256(ss, ws4);
  float r = rsqrtf(ss * (1.f / D_SZ) + 1e-6f);
  size_t base = (size_t)bt * D_SZ + threadIdx.x;
#pragma unroll
  for (int i = 0; i < 3; i++) {
    float o = v[i] * r;
    x[base + i * 256] = o;
    x0[base + i * 256] = o;
  }
}

// -------- x = a*x + b*x0 (layer>=0) then xn = RMSNorm(x). layer<0: norm only --------
__global__ __launch_bounds__(256) void resid_norm_k(
    float* __restrict__ x, const float* __restrict__ x0, float* __restrict__ xn,
    const float* __restrict__ rl, const float* __restrict__ xl, int layer) {
  __shared__ float ws4[4];
  int bt = blockIdx.x;
  float a = 1.f, b = 0.f;
  if (layer >= 0) { a = rl[layer]; b = xl[layer]; }
  size_t base = (size_t)bt * D_SZ + threadIdx.x;
  float v[3]; float ss = 0.f;
#pragma unroll
  for (int i = 0; i < 3; i++) {
    float nv = a * x[base + i * 256] + b * x0[base + i * 256];
    v[i] = nv; ss += nv * nv;
    if (layer >= 0) x[base + i * 256] = nv;
  }
  ss = block_reduce_sum_256(ss, ws4);
  float r = rsqrtf(ss * (1.f / D_SZ) + 1e-6f);
#pragma unroll
  for (int i = 0; i < 3; i++) xn[base + i * 256] = v[i] * r;
}

// ---------------- RoPE + per-head RMSNorm for q (12 heads) and k (4 heads) ----------------
// grid: (B*T, H+KVH), block: 64 (one wave per head vector)
__global__ __launch_bounds__(64) void rope_norm_k(float* __restrict__ q, float* __restrict__ k) {
  int bt = blockIdx.x;
  int slot = blockIdx.y;
  int t = bt & (T_SEQ - 1);
  float* p;
  if (slot < H_N) p = q + (size_t)bt * D_SZ + slot * HD_SZ;
  else            p = k + (size_t)bt * KVD_SZ + (slot - H_N) * HD_SZ;
  int d = threadIdx.x;
  float self = p[d];
  float partner = p[d ^ 32];
  int j = d & 31;
  float inv = powf(10000.f, -(float)(2 * j) * (1.f / HD_SZ));
  float ang = (float)t * inv;
  float c = cosf(ang), s = sinf(ang);
  // d<32: x1=self, x2=partner -> x1*c + x2*s ; d>=32: x1=partner, x2=self -> -x1*s + x2*c
  float out = (d < 32) ? (self * c + partner * s) : (self * c - partner * s);
  float ss = out * out;
#pragma unroll
  for (int o = 32; o; o >>= 1) ss += __shfl_xor(ss, o, 64);
  float r = rsqrtf(ss * (1.f / HD_SZ) + 1e-6f);
  p[d] = out * r;
}

// ---------------- value-embedding add: v += 2*sigmoid(xn[:32]·g[kh]) * ve[tok] ----------------
__global__ __launch_bounds__(256) void ve_add_k(
    float* __restrict__ v, const float* __restrict__ xn, const int* __restrict__ idx,
    const float* __restrict__ vt, const float* __restrict__ vg) {
  int bt = blockIdx.x;
  int kh = threadIdx.x >> 6;
  const float* xr = xn + (size_t)bt * D_SZ;
  const float* gr = vg + kh * 32;
  float dot = 0.f;
#pragma unroll
  for (int c = 0; c < 32; c++) dot += xr[c] * gr[c];
  float g = 2.f / (1.f + expf(-dot));
  int tok = idx[bt];
  v[(size_t)bt * KVD_SZ + threadIdx.x] += g * vt[(size_t)tok * KVD_SZ + threadIdx.x];
}

// ---------------- flash-style windowed-causal GQA attention ----------------
// Q-tile 32, K-tile 64. grid (T/32, H, B), block 256.
#define QT 32
#define KT 64
__global__ __launch_bounds__(256) void attn_k(
    const float* __restrict__ qg, const float* __restrict__ kg,
    const float* __restrict__ vg, float* __restrict__ yg, int window) {
  __shared__ float Qs[QT][HD_SZ + 1];
  __shared__ float Ks[KT][HD_SZ + 1];
  __shared__ float Vs[KT][HD_SZ];
  __shared__ float S[QT][KT + 1];
  __shared__ float m_s[QT], l_s[QT], alpha_s[QT];

  int qt0 = blockIdx.x * QT;
  int h   = blockIdx.y;
  int b   = blockIdx.z;
  int kh  = h / (H_N / KVH_N);
  int tid = threadIdx.x;

  for (int e = tid; e < QT * HD_SZ; e += 256) {
    int qi = e >> 6, d = e & 63;
    Qs[qi][d] = qg[(size_t)(b * T_SEQ + qt0 + qi) * D_SZ + h * HD_SZ + d] * 0.125f;
  }
  if (tid < QT) { m_s[tid] = -INFINITY; l_s[tid] = 0.f; }

  int gq = tid >> 4;        // 0..15: owns q rows 2*gq, 2*gq+1
  int tx = tid & 15;        // 0..15: 4-wide col group
  int qi0 = gq * 2;
  float o_acc[2][4] = {{0,0,0,0},{0,0,0,0}};

  int klo = qt0 - window + 1; if (klo < 0) klo = 0;
  int khi = qt0 + QT - 1;
  int kt_start = klo & ~(KT - 1);

  for (int kt = kt_start; kt <= khi; kt += KT) {
    __syncthreads();   // protect Ks/Vs/S from previous iteration readers
    for (int e = tid; e < KT * HD_SZ; e += 256) {
      int kj = e >> 6, d = e & 63;
      size_t gidx = (size_t)(b * T_SEQ + kt + kj) * KVD_SZ + kh * HD_SZ + d;
      Ks[kj][d] = kg[gidx];
      Vs[kj][d] = vg[gidx];
    }
    __syncthreads();

    // scores: 2 (q) x 4 (k) per thread
    int kj0 = tx * 4;
    float sc[2][4] = {{0,0,0,0},{0,0,0,0}};
    for (int d = 0; d < HD_SZ; d++) {
      float a0 = Qs[qi0][d], a1 = Qs[qi0 + 1][d];
      float b0 = Ks[kj0][d], b1 = Ks[kj0 + 1][d], b2 = Ks[kj0 + 2][d], b3 = Ks[kj0 + 3][d];
      sc[0][0] += a0 * b0; sc[0][1] += a0 * b1; sc[0][2] += a0 * b2; sc[0][3] += a0 * b3;
      sc[1][0] += a1 * b0; sc[1][1] += a1 * b1; sc[1][2] += a1 * b2; sc[1][3] += a1 * b3;
    }
#pragma unroll
    for (int r = 0; r < 2; r++) {
      int qpos = qt0 + qi0 + r;
#pragma unroll
      for (int j = 0; j < 4; j++) {
        int diff = qpos - (kt + kj0 + j);
        if (diff < 0 || diff >= window) sc[r][j] = -INFINITY;
      }
    }
    // online softmax: 16 lanes (same gq) cooperate per row pair
#pragma unroll
    for (int r = 0; r < 2; r++) {
      int row = qi0 + r;
      float m = fmaxf(fmaxf(sc[r][0], sc[r][1]), fmaxf(sc[r][2], sc[r][3]));
#pragma unroll
      for (int o = 1; o < 16; o <<= 1) m = fmaxf(m, __shfl_xor(m, o, 64));
      float m_old = m_s[row];
      float m_new = fmaxf(m_old, m);
      float alpha, psum = 0.f;
      if (m_new == -INFINITY) {     // fully-masked so far: keep state, write zeros
        alpha = 1.f;
#pragma unroll
        for (int j = 0; j < 4; j++) S[row][kj0 + j] = 0.f;
      } else {
        alpha = expf(m_old - m_new);   // m_old=-inf -> 0
#pragma unroll
        for (int j = 0; j < 4; j++) {
          float p = expf(sc[r][j] - m_new);   // masked -> exp(-inf)=0
          S[row][kj0 + j] = p;
          psum += p;
        }
      }
#pragma unroll
      for (int o = 1; o < 16; o <<= 1) psum += __shfl_xor(psum, o, 64);
      if (tx == 0) {
        m_s[row] = m_new;
        alpha_s[row] = alpha;
        l_s[row] = alpha * l_s[row] + psum;
      }
    }
    __syncthreads();

    // PV: 2 (q) x 4 (d) per thread
    int d0 = tx * 4;
#pragma unroll
    for (int r = 0; r < 2; r++) {
      float al = alpha_s[qi0 + r];
#pragma unroll
      for (int c = 0; c < 4; c++) o_acc[r][c] *= al;
    }
    for (int kj = 0; kj < KT; kj++) {
      float p0 = S[qi0][kj], p1 = S[qi0 + 1][kj];
      float v0 = Vs[kj][d0], v1 = Vs[kj][d0 + 1], v2 = Vs[kj][d0 + 2], v3 = Vs[kj][d0 + 3];
      o_acc[0][0] += p0 * v0; o_acc[0][1] += p0 * v1; o_acc[0][2] += p0 * v2; o_acc[0][3] += p0 * v3;
      o_acc[1][0] += p1 * v0; o_acc[1][1] += p1 * v1; o_acc[1][2] += p1 * v2; o_acc[1][3] += p1 * v3;
    }
  }

  int d0 = tx * 4;
#pragma unroll
  for (int r = 0; r < 2; r++) {
    float inv_l = 1.f / l_s[qi0 + r];
    size_t yi = (size_t)(b * T_SEQ + qt0 + qi0 + r) * D_SZ + h * HD_SZ + d0;
    yg[yi + 0] = o_acc[r][0] * inv_l;
    yg[yi + 1] = o_acc[r][1] * inv_l;
    yg[yi + 2] = o_acc[r][2] * inv_l;
    yg[yi + 3] = o_acc[r][3] * inv_l;
  }
}

// ---------------- fp32 tiled GEMM: Y[M][N] (op)= X[M][K] · W[N][K]^T ----------------
// EPI: 0 = store, 1 = Y += acc (residual), 2 = relu(acc)^2, 3 = 15*tanh(acc/15)
template <int EPI>
__global__ __launch_bounds__(256) void gemm_nt_k(
    const float* __restrict__ X, const float* __restrict__ W, float* __restrict__ Y,
    int M, int N, int K) {
  __shared__ float Xs[16][68];
  __shared__ float Ws[16][68];
  int n0 = blockIdx.x * 64;
  int m0 = blockIdx.y * 64;
  int tid = threadIdx.x;
  int tx = tid & 15, ty = tid >> 4;
  int lm = tid >> 2, lk = (tid & 3) << 2;
  float acc[4][4] = {};

  const float* xp = X + (size_t)(m0 + lm) * K + lk;
  const float* wp = W + (size_t)(n0 + lm) * K + lk;

  for (int k0 = 0; k0 < K; k0 += 16) {
    float4 xv = *(const float4*)(xp + k0);
    float4 wv = *(const float4*)(wp + k0);
    __syncthreads();
    Xs[lk + 0][lm] = xv.x; Xs[lk + 1][lm] = xv.y; Xs[lk + 2][lm] = xv.z; Xs[lk + 3][lm] = xv.w;
    Ws[lk + 0][lm] = wv.x; Ws[lk + 1][lm] = wv.y; Ws[lk + 2][lm] = wv.z; Ws[lk + 3][lm] = wv.w;
    __syncthreads();
#pragma unroll
    for (int kk = 0; kk < 16; kk++) {
      float4 av = *(const float4*)(&Xs[kk][ty * 4]);
      float4 bv = *(const float4*)(&Ws[kk][tx * 4]);
      acc[0][0] += av.x * bv.x; acc[0][1] += av.x * bv.y; acc[0][2] += av.x * bv.z; acc[0][3] += av.x * bv.w;
      acc[1][0] += av.y * bv.x; acc[1][1] += av.y * bv.y; acc[1][2] += av.y * bv.z; acc[1][3] += av.y * bv.w;
      acc[2][0] += av.z * bv.x; acc[2][1] += av.z * bv.y; acc[2][2] += av.z * bv.z; acc[2][3] += av.z * bv.w;
      acc[3][0] += av.w * bv.x; acc[3][1] += av.w * bv.y; acc[3][2] += av.w * bv.z; acc[3][3] += av.w * bv.w;
    }
  }

  int row0 = m0 + ty * 4;
  int col  = n0 + tx * 4;
#pragma unroll
  for (int i = 0; i < 4; i++) {
    float4 r;
    r.x = acc[i][0]; r.y = acc[i][1]; r.z = acc[i][2]; r.w = acc[i][3];
    float* yp = Y + (size_t)(row0 + i) * N + col;
    if (EPI == 1) {
      float4 old = *(const float4*)yp;
      r.x += old.x; r.y += old.y; r.z += old.z; r.w += old.w;
    } else if (EPI == 2) {
      r.x = fmaxf(r.x, 0.f); r.x *= r.x;
      r.y = fmaxf(r.y, 0.f); r.y *= r.y;
      r.z = fmaxf(r.z, 0.f); r.z *= r.z;
      r.w = fmaxf(r.w, 0.f); r.w *= r.w;
    } else if (EPI == 3) {
      r.x = 15.f * tanhf(r.x * (1.f / 15.f));
      r.y = 15.f * tanhf(r.y * (1.f / 15.f));
      r.z = 15.f * tanhf(r.z * (1.f / 15.f));
      r.w = 15.f * tanhf(r.w * (1.f / 15.f));
    }
    *(float4*)yp = r;
  }
}

// ---------------- host-side launch ----------------
extern "C" void kernel_launch(void* const* d_in, const int* in_sizes, int n_in,
                              void* d_out, int out_size, void* d_ws, size_t ws_size,
                              hipStream_t stream) {
  (void)in_sizes; (void)n_in; (void)out_size; (void)ws_size;
  const int*   idx = (const int*)d_in[0];
  const float* wte = (const float*)d_in[1];
  const float* Wq  = (const float*)d_in[2];
  const float* Wk  = (const float*)d_in[3];
  const float* Wv  = (const float*)d_in[4];
  const float* Wo  = (const float*)d_in[5];
  const float* Wfc = (const float*)d_in[6];
  const float* Wpr = (const float*)d_in[7];
  const float* vet = (const float*)d_in[8];
  const float* veg = (const float*)d_in[9];
  const float* rl  = (const float*)d_in[10];
  const float* xl  = (const float*)d_in[11];
  const float* lmw = (const float*)d_in[12];
  float* out = (float*)d_out;

  float* ws = (float*)d_ws;
  float* x    = ws;                       // M_TOK * 768
  float* x0   = x  + (size_t)M_TOK * D_SZ;
  float* xn   = x0 + (size_t)M_TOK * D_SZ;
  float* q    = xn + (size_t)M_TOK * D_SZ;
  float* y    = q  + (size_t)M_TOK * D_SZ;
  float* kbuf = y  + (size_t)M_TOK * D_SZ;   // M_TOK * 256
  float* vbuf = kbuf + (size_t)M_TOK * KVD_SZ;
  float* hbuf = vbuf + (size_t)M_TOK * KVD_SZ;  // M_TOK * 3072

  const int windows[L_N] = {T_SEQ / 2, T_SEQ, T_SEQ / 2, T_SEQ, T_SEQ / 2, T_SEQ};
  const int ve_map[L_N]  = {-1, 0, -1, 1, -1, 2};

  embed_norm_k<<<M_TOK, 256, 0, stream>>>(idx, wte, x, x0);

  for (int i = 0; i < L_N; i++) {
    resid_norm_k<<<M_TOK, 256, 0, stream>>>(x, x0, xn, rl, xl, i);

    gemm_nt_k<0><<<dim3(D_SZ / 64, M_TOK / 64), 256, 0, stream>>>(
        xn, Wq + (size_t)i * D_SZ * D_SZ, q, M_TOK, D_SZ, D_SZ);
    gemm_nt_k<0><<<dim3(KVD_SZ / 64, M_TOK / 64), 256, 0, stream>>>(
        xn, Wk + (size_t)i * KVD_SZ * D_SZ, kbuf, M_TOK, KVD_SZ, D_SZ);
    gemm_nt_k<0><<<dim3(KVD_SZ / 64, M_TOK / 64), 256, 0, stream>>>(
        xn, Wv + (size_t)i * KVD_SZ * D_SZ, vbuf, M_TOK, KVD_SZ, D_SZ);

    if (ve_map[i] >= 0) {
      ve_add_k<<<M_TOK, 256, 0, stream>>>(
          vbuf, xn, idx, vet + (size_t)ve_map[i] * V_SZ * KVD_SZ,
          veg + (size_t)ve_map[i] * KVH_N * 32);
    }

    rope_norm_k<<<dim3(M_TOK, H_N + KVH_N), 64, 0, stream>>>(q, kbuf);

    attn_k<<<dim3(T_SEQ / QT, H_N, B_SZ), 256, 0, stream>>>(q, kbuf, vbuf, y, windows[i]);

    gemm_nt_k<1><<<dim3(D_SZ / 64, M_TOK / 64), 256, 0, stream>>>(
        y, Wo + (size_t)i * D_SZ * D_SZ, x, M_TOK, D_SZ, D_SZ);

    resid_norm_k<<<M_TOK, 256, 0, stream>>>(x, x0, xn, rl, xl, -1);

    gemm_nt_k<2><<<dim3(4 * D_SZ / 64, M_TOK / 64), 256, 0, stream>>>(
        xn, Wfc + (size_t)i * 4 * D_SZ * D_SZ, hbuf, M_TOK, 4 * D_SZ, D_SZ);

    gemm_nt_k<1><<<dim3(D_SZ / 64, M_TOK / 64), 256, 0, stream>>>(
        hbuf, Wpr + (size_t)i * D_SZ * 4 * D_SZ, x, M_TOK, D_SZ, 4 * D_SZ);
  }

  resid_norm_k<<<M_TOK, 256, 0, stream>>>(x, x0, xn, rl, xl, -1);
  gemm_nt_k<3><<<dim3(V_SZ / 64, M_TOK / 64), 256, 0, stream>>>(
      xn, lmw, out, M_TOK, V_SZ, D_SZ);
}